// Round 1
// baseline (74.361 us; speedup 1.0000x reference)
//
#include <hip/hip_runtime.h>

#define BB 8
#define CC 512
#define NN 2048
#define SEM 32
#define BN_EPS 1e-5f

// ---------------- K1: per-(b,c) spatial mean ----------------
__global__ __launch_bounds__(256) void k_avg(const float* __restrict__ x,
                                             float* __restrict__ avg) {
    int bc = blockIdx.x;
    const float4* x4 = reinterpret_cast<const float4*>(x + (size_t)bc * NN);
    int tid = threadIdx.x;
    float4 a = x4[tid];
    float4 b = x4[tid + 256];
    float s = a.x + a.y + a.z + a.w + b.x + b.y + b.z + b.w;
    for (int o = 32; o > 0; o >>= 1) s += __shfl_down(s, o);
    __shared__ float red[4];
    int wave = tid >> 6, lane = tid & 63;
    if (lane == 0) red[wave] = s;
    __syncthreads();
    if (tid == 0) avg[bc] = (red[0] + red[1] + red[2] + red[3]) * (1.0f / NN);
}

// ---------------- K2: per-pixel projections g/theta/phi ----------------
__global__ __launch_bounds__(256) void k_proj(const float* __restrict__ x,
    const float* __restrict__ gw, const float* __restrict__ gb,
    const float* __restrict__ tw, const float* __restrict__ tb,
    const float* __restrict__ pw, const float* __restrict__ pb,
    float* __restrict__ gx, float* __restrict__ tx, float* __restrict__ px) {
    __shared__ float4 wpack[CC];
    int tid = threadIdx.x;
    for (int c = tid; c < CC; c += 256)
        wpack[c] = make_float4(gw[c], tw[c], pw[c], 0.f);
    __syncthreads();
    int b = blockIdx.x >> 3;                 // 8 blocks of 256 pixels per sample
    int i = ((blockIdx.x & 7) << 8) + tid;
    const float* xp = x + (size_t)b * CC * NN + i;
    float ag = 0.f, at = 0.f, ap = 0.f;
    #pragma unroll 8
    for (int c = 0; c < CC; ++c) {
        float v = xp[(size_t)c * NN];
        float4 w = wpack[c];
        ag = fmaf(w.x, v, ag);
        at = fmaf(w.y, v, at);
        ap = fmaf(w.z, v, ap);
    }
    int o = b * NN + i;
    gx[o] = ag + gb[0];
    tx[o] = at + tb[0];
    px[o] = ap + pb[0];
}

// ---------------- K3: SE gate -> folded affine coeffs; phi min/max ----------------
__global__ __launch_bounds__(256) void k_small(
    const float* __restrict__ avg, const float* __restrict__ px,
    const float* __restrict__ se1w, const float* __restrict__ se1b,
    const float* __restrict__ se2w, const float* __restrict__ se2b,
    const float* __restrict__ Ww, const float* __restrict__ Wb,
    const float* __restrict__ gamma, const float* __restrict__ beta,
    const float* __restrict__ mean, const float* __restrict__ var,
    float* __restrict__ Ac, float* __restrict__ Dc,
    float* __restrict__ pmaxv, float* __restrict__ pminv) {
    int b = blockIdx.x, tid = threadIdx.x;
    __shared__ float sA[CC];
    __shared__ float sM[SEM];
    __shared__ float rmax[4], rmin[4];
    for (int c = tid; c < CC; c += 256) sA[c] = avg[b * CC + c];
    // phi min/max over the sample
    float mx = -1e30f, mn = 1e30f;
    for (int j = tid; j < NN; j += 256) {
        float v = px[b * NN + j];
        mx = fmaxf(mx, v);
        mn = fminf(mn, v);
    }
    for (int o = 32; o > 0; o >>= 1) {
        mx = fmaxf(mx, __shfl_down(mx, o));
        mn = fminf(mn, __shfl_down(mn, o));
    }
    int wave = tid >> 6, lane = tid & 63;
    if (lane == 0) { rmax[wave] = mx; rmin[wave] = mn; }
    __syncthreads();
    if (tid == 0) {
        pmaxv[b] = fmaxf(fmaxf(rmax[0], rmax[1]), fmaxf(rmax[2], rmax[3]));
        pminv[b] = fminf(fminf(rmin[0], rmin[1]), fminf(rmin[2], rmin[3]));
    }
    // SE layer 1: 32 mids, serial over C (tiny kernel, fine)
    if (tid < SEM) {
        float s = 0.f;
        for (int c = 0; c < CC; ++c) s = fmaf(sA[c], se1w[tid * CC + c], s);
        s += se1b[tid];
        sM[tid] = fmaxf(s, 0.f);
    }
    __syncthreads();
    // SE layer 2 + sigmoid + fold BN/W into per-(b,c) affine
    for (int c = tid; c < CC; c += 256) {
        float s = 0.f;
        #pragma unroll
        for (int m = 0; m < SEM; ++m) s = fmaf(sM[m], se2w[c * SEM + m], s);
        s += se2b[c];
        float wcw = 1.f / (1.f + __expf(-s));
        float inv = gamma[c] * rsqrtf(var[c] + BN_EPS);
        Ac[b * CC + c] = wcw * Ww[c] * inv;
        Dc[b * CC + c] = wcw * ((Wb[c] - mean[c]) * inv + beta[c]);
    }
}

// ---------------- K4: rank-1 softmax row reduce: y[b,i] ----------------
__global__ __launch_bounds__(256) void k_y(
    const float* __restrict__ gx, const float* __restrict__ tx,
    const float* __restrict__ px, const float* __restrict__ pmaxv,
    const float* __restrict__ pminv, float* __restrict__ y) {
    __shared__ float2 pg[NN];
    int b = blockIdx.x >> 9;                 // 512 blocks per sample
    int tid = threadIdx.x;
    for (int j = tid; j < NN; j += 256)
        pg[j] = make_float2(px[b * NN + j], gx[b * NN + j]);
    __syncthreads();
    int wave = tid >> 6, lane = tid & 63;
    int i = ((blockIdx.x & 511) << 2) + wave;  // 4 rows per block, 1 per wave
    float theta = tx[b * NN + i];
    float m = theta >= 0.f ? theta * pmaxv[b] : theta * pminv[b];
    float s = 0.f, sg = 0.f;
    #pragma unroll 8
    for (int j = lane; j < NN; j += 64) {
        float2 v = pg[j];
        float e = __expf(fmaf(theta, v.x, -m));
        s += e;
        sg = fmaf(e, v.y, sg);
    }
    for (int o = 32; o > 0; o >>= 1) {
        s += __shfl_down(s, o);
        sg += __shfl_down(sg, o);
    }
    if (lane == 0) y[b * NN + i] = sg / s;
}

// ---------------- K5: epilogue out = A*y + D + x ----------------
__global__ __launch_bounds__(256) void k_out(
    const float* __restrict__ x, const float* __restrict__ y,
    const float* __restrict__ Ac, const float* __restrict__ Dc,
    float* __restrict__ out) {
    int bc = blockIdx.x;
    int b = bc >> 9;
    float a = Ac[bc], d = Dc[bc];
    const float4* x4 = reinterpret_cast<const float4*>(x) + (size_t)bc * (NN / 4);
    const float4* y4 = reinterpret_cast<const float4*>(y) + (size_t)b * (NN / 4);
    float4* o4 = reinterpret_cast<float4*>(out) + (size_t)bc * (NN / 4);
    int tid = threadIdx.x;
    #pragma unroll
    for (int k = 0; k < 2; ++k) {
        int idx = k * 256 + tid;
        float4 xv = x4[idx], yv = y4[idx], ov;
        ov.x = fmaf(a, yv.x, d) + xv.x;
        ov.y = fmaf(a, yv.y, d) + xv.y;
        ov.z = fmaf(a, yv.z, d) + xv.z;
        ov.w = fmaf(a, yv.w, d) + xv.w;
        o4[idx] = ov;
    }
}

extern "C" void kernel_launch(void* const* d_in, const int* in_sizes, int n_in,
                              void* d_out, int out_size, void* d_ws, size_t ws_size,
                              hipStream_t stream) {
    const float* x    = (const float*)d_in[0];
    const float* gw   = (const float*)d_in[1];
    const float* gb   = (const float*)d_in[2];
    const float* tw   = (const float*)d_in[3];
    const float* tb   = (const float*)d_in[4];
    const float* pw   = (const float*)d_in[5];
    const float* pb   = (const float*)d_in[6];
    const float* Ww   = (const float*)d_in[7];
    const float* Wb   = (const float*)d_in[8];
    const float* gam  = (const float*)d_in[9];
    const float* bet  = (const float*)d_in[10];
    const float* mu   = (const float*)d_in[11];
    const float* var  = (const float*)d_in[12];
    const float* se1w = (const float*)d_in[13];
    const float* se1b = (const float*)d_in[14];
    const float* se2w = (const float*)d_in[15];
    const float* se2b = (const float*)d_in[16];

    float* ws   = (float*)d_ws;
    float* avg  = ws; ws += BB * CC;
    float* gx   = ws; ws += BB * NN;
    float* tx   = ws; ws += BB * NN;
    float* px   = ws; ws += BB * NN;
    float* y    = ws; ws += BB * NN;
    float* Ac   = ws; ws += BB * CC;
    float* Dc   = ws; ws += BB * CC;
    float* pmax = ws; ws += BB;
    float* pmin = ws; ws += BB;
    float* out  = (float*)d_out;

    k_avg  <<<BB * CC, 256, 0, stream>>>(x, avg);
    k_proj <<<BB * 8, 256, 0, stream>>>(x, gw, gb, tw, tb, pw, pb, gx, tx, px);
    k_small<<<BB, 256, 0, stream>>>(avg, px, se1w, se1b, se2w, se2b, Ww, Wb,
                                    gam, bet, mu, var, Ac, Dc, pmax, pmin);
    k_y    <<<BB * 512, 256, 0, stream>>>(gx, tx, px, pmax, pmin, y);
    k_out  <<<BB * CC, 256, 0, stream>>>(x, y, Ac, Dc, out);
}

// Round 2
// 63.503 us; speedup vs baseline: 1.1710x; 1.1710x over previous
//
#include <hip/hip_runtime.h>

#define BB 8
#define CC 512
#define NN 2048
#define SEM 32
#define BN_EPS 1e-5f

// ---------------- K1: fused per-(b,c) mean + per-pixel projections ----------------
// grid = 4096 blocks. Every block reduces one (b,c) row for avg.
// Blocks with (blockIdx & 15)==0 additionally compute the g/theta/phi projections
// for a 64-pixel strip (256 such blocks; wave-per-channel-group, 256B coalesced loads).
__global__ __launch_bounds__(256) void k1(const float* __restrict__ x,
    const float* __restrict__ gw, const float* __restrict__ tw, const float* __restrict__ pw,
    const float* __restrict__ gb, const float* __restrict__ tb, const float* __restrict__ pb,
    float* __restrict__ avg, float* __restrict__ gx, float* __restrict__ tx,
    float* __restrict__ px)
{
    int tid = threadIdx.x;
    int wave = tid >> 6, lane = tid & 63;

    // ---- avg phase: one (b,c) row per block ----
    {
        int bc = blockIdx.x;
        const float4* x4 = reinterpret_cast<const float4*>(x + (size_t)bc * NN);
        float4 a = x4[tid];
        float4 b = x4[tid + 256];
        float s = a.x + a.y + a.z + a.w + b.x + b.y + b.z + b.w;
        for (int o = 32; o > 0; o >>= 1) s += __shfl_down(s, o);
        __shared__ float red[4];
        if (lane == 0) red[wave] = s;
        __syncthreads();
        if (tid == 0) avg[bc] = (red[0] + red[1] + red[2] + red[3]) * (1.0f / NN);
    }

    if ((blockIdx.x & 15) != 0) return;   // block-uniform exit, safe

    // ---- proj phase: 256 blocks, 64-pixel strip each ----
    int pid = blockIdx.x >> 4;            // 0..255
    int b  = pid >> 5;                    // 32 strips per sample
    int i0 = (pid & 31) << 6;

    __shared__ float4 wpack[CC];
    for (int c = tid; c < CC; c += 256)
        wpack[c] = make_float4(gw[c], tw[c], pw[c], 0.f);
    __syncthreads();

    const float* xp = x + (size_t)b * CC * NN + i0 + lane;
    float ag = 0.f, at_ = 0.f, ap = 0.f;
    #pragma unroll 8
    for (int c = wave; c < CC; c += 4) {   // wave w: channels w, w+4, ...
        float v = xp[(size_t)c * NN];
        float4 w = wpack[c];
        ag  = fmaf(w.x, v, ag);
        at_ = fmaf(w.y, v, at_);
        ap  = fmaf(w.z, v, ap);
    }
    __shared__ float pr[4][64][4];
    pr[wave][lane][0] = ag;
    pr[wave][lane][1] = at_;
    pr[wave][lane][2] = ap;
    __syncthreads();
    if (tid < 64) {
        float g_ = 0.f, t_ = 0.f, p_ = 0.f;
        #pragma unroll
        for (int w = 0; w < 4; ++w) {
            g_ += pr[w][tid][0];
            t_ += pr[w][tid][1];
            p_ += pr[w][tid][2];
        }
        int o = b * NN + i0 + tid;
        gx[o] = g_ + gb[0];
        tx[o] = t_ + tb[0];
        px[o] = p_ + pb[0];
    }
}

// ---------------- K2: rank-1 softmax y (no-max, clamped) + SE/affine fold ----------------
// grid = 2048 + 8. Blocks [0,2048): 8 softmax rows each (2 rows per wave).
// Blocks [2048,2056): per-sample SE gate -> folded affine Ac/Dc.
__global__ __launch_bounds__(256) void k2(
    const float* __restrict__ gx, const float* __restrict__ tx,
    const float* __restrict__ px, const float* __restrict__ avg,
    const float* __restrict__ se1w, const float* __restrict__ se1b,
    const float* __restrict__ se2w, const float* __restrict__ se2b,
    const float* __restrict__ Ww, const float* __restrict__ Wb,
    const float* __restrict__ gamma, const float* __restrict__ beta,
    const float* __restrict__ mean, const float* __restrict__ var,
    float* __restrict__ y, float* __restrict__ Ac, float* __restrict__ Dc)
{
    int tid = threadIdx.x;

    if (blockIdx.x >= 2048) {
        // ---- SE / affine path ----
        int b = blockIdx.x - 2048;
        __shared__ float sA[CC];
        __shared__ float sP[SEM][8];
        __shared__ float sM[SEM];
        for (int c = tid; c < CC; c += 256) sA[c] = avg[b * CC + c];
        __syncthreads();
        // SE1: 32 mids x 8 partial-threads
        {
            int m = tid >> 3, sub = tid & 7;
            const float* w1 = se1w + m * CC + sub * 64;
            const float* a1 = sA + sub * 64;
            float s = 0.f;
            #pragma unroll
            for (int k = 0; k < 64; ++k) s = fmaf(a1[k], w1[k], s);
            sP[m][sub] = s;
        }
        __syncthreads();
        if (tid < SEM) {
            float t = 0.f;
            #pragma unroll
            for (int k = 0; k < 8; ++k) t += sP[tid][k];
            sM[tid] = fmaxf(t + se1b[tid], 0.f);
        }
        __syncthreads();
        for (int c = tid; c < CC; c += 256) {
            float s2 = 0.f;
            #pragma unroll
            for (int m = 0; m < SEM; ++m) s2 = fmaf(sM[m], se2w[c * SEM + m], s2);
            s2 += se2b[c];
            float wcw = 1.f / (1.f + __expf(-s2));
            float inv = gamma[c] * rsqrtf(var[c] + BN_EPS);
            Ac[b * CC + c] = wcw * Ww[c] * inv;
            Dc[b * CC + c] = wcw * ((Wb[c] - mean[c]) * inv + beta[c]);
        }
        return;
    }

    // ---- softmax-y path ----
    __shared__ float2 pg[NN];
    int b  = blockIdx.x >> 8;                 // 256 blocks per sample
    int i0 = (blockIdx.x & 255) << 3;         // 8 rows per block
    for (int j = tid; j < NN; j += 256)
        pg[j] = make_float2(px[b * NN + j], gx[b * NN + j]);
    __syncthreads();

    int wave = tid >> 6, lane = tid & 63;
    int r0 = i0 + wave * 2, r1 = r0 + 1;
    float t0 = tx[b * NN + r0];
    float t1 = tx[b * NN + r1];
    float s0 = 0.f, sg0 = 0.f, s1 = 0.f, sg1 = 0.f;
    #pragma unroll 8
    for (int j = lane; j < NN; j += 64) {
        float2 v = pg[j];
        float e0 = __expf(fminf(t0 * v.x, 80.f));
        float e1 = __expf(fminf(t1 * v.x, 80.f));
        s0 += e0; sg0 = fmaf(e0, v.y, sg0);
        s1 += e1; sg1 = fmaf(e1, v.y, sg1);
    }
    for (int o = 32; o > 0; o >>= 1) {
        s0 += __shfl_down(s0, o);   sg0 += __shfl_down(sg0, o);
        s1 += __shfl_down(s1, o);   sg1 += __shfl_down(sg1, o);
    }
    if (lane == 0) {
        y[b * NN + r0] = sg0 / s0;
        y[b * NN + r1] = sg1 / s1;
    }
}

// ---------------- K3: epilogue out = A*y + D + x ----------------
__global__ __launch_bounds__(256) void k3(
    const float* __restrict__ x, const float* __restrict__ y,
    const float* __restrict__ Ac, const float* __restrict__ Dc,
    float* __restrict__ out)
{
    int bc = blockIdx.x;
    int b = bc >> 9;
    float a = Ac[bc], d = Dc[bc];
    const float4* x4 = reinterpret_cast<const float4*>(x) + (size_t)bc * (NN / 4);
    const float4* y4 = reinterpret_cast<const float4*>(y) + (size_t)b * (NN / 4);
    float4* o4 = reinterpret_cast<float4*>(out) + (size_t)bc * (NN / 4);
    int tid = threadIdx.x;
    #pragma unroll
    for (int k = 0; k < 2; ++k) {
        int idx = k * 256 + tid;
        float4 xv = x4[idx], yv = y4[idx], ov;
        ov.x = fmaf(a, yv.x, d) + xv.x;
        ov.y = fmaf(a, yv.y, d) + xv.y;
        ov.z = fmaf(a, yv.z, d) + xv.z;
        ov.w = fmaf(a, yv.w, d) + xv.w;
        o4[idx] = ov;
    }
}

extern "C" void kernel_launch(void* const* d_in, const int* in_sizes, int n_in,
                              void* d_out, int out_size, void* d_ws, size_t ws_size,
                              hipStream_t stream) {
    const float* x    = (const float*)d_in[0];
    const float* gw   = (const float*)d_in[1];
    const float* gb   = (const float*)d_in[2];
    const float* tw   = (const float*)d_in[3];
    const float* tb   = (const float*)d_in[4];
    const float* pw   = (const float*)d_in[5];
    const float* pb   = (const float*)d_in[6];
    const float* Ww   = (const float*)d_in[7];
    const float* Wb   = (const float*)d_in[8];
    const float* gam  = (const float*)d_in[9];
    const float* bet  = (const float*)d_in[10];
    const float* mu   = (const float*)d_in[11];
    const float* var  = (const float*)d_in[12];
    const float* se1w = (const float*)d_in[13];
    const float* se1b = (const float*)d_in[14];
    const float* se2w = (const float*)d_in[15];
    const float* se2b = (const float*)d_in[16];

    float* ws   = (float*)d_ws;
    float* avg  = ws; ws += BB * CC;
    float* gx   = ws; ws += BB * NN;
    float* tx   = ws; ws += BB * NN;
    float* px   = ws; ws += BB * NN;
    float* y    = ws; ws += BB * NN;
    float* Ac   = ws; ws += BB * CC;
    float* Dc   = ws; ws += BB * CC;
    float* out  = (float*)d_out;

    k1<<<BB * CC, 256, 0, stream>>>(x, gw, tw, pw, gb, tb, pb, avg, gx, tx, px);
    k2<<<2048 + BB, 256, 0, stream>>>(gx, tx, px, avg, se1w, se1b, se2w, se2b,
                                      Ww, Wb, gam, bet, mu, var, y, Ac, Dc);
    k3<<<BB * CC, 256, 0, stream>>>(x, y, Ac, Dc, out);
}

// Round 3
// 42.511 us; speedup vs baseline: 1.7492x; 1.4938x over previous
//
#include <hip/hip_runtime.h>

#define BB 8
#define CC 512
#define NN 2048
#define SEM 32
#define BN_EPS 1e-5f

#define NCC 16          // channels per chunk
#define NCHUNK (CC / NCC)   // 32 chunks
#define PIX 1024        // pixels per chunk (256 threads * float4)

// ---------------- K1: full-BW pass: proj partials + avg partials ----------------
// grid = BB * NCHUNK * 2 = 512 blocks. Block handles (b, cc: 16 channels, ic: 1024 pixels).
__global__ __launch_bounds__(256) void k1(const float* __restrict__ x,
    const float* __restrict__ gw, const float* __restrict__ tw, const float* __restrict__ pw,
    float* __restrict__ pp,      // [3][BB][2][NCHUNK][PIX]
    float* __restrict__ avgp)    // [BB*CC][8]
{
    int tid = threadIdx.x;
    int wave = tid >> 6, lane = tid & 63;
    int blk = blockIdx.x;
    int ic = blk & 1;
    int cc = (blk >> 1) & (NCHUNK - 1);
    int b  = blk >> 6;
    int c0 = cc * NCC;

    const float4* xp = reinterpret_cast<const float4*>(x)
                     + ((size_t)(b * CC + c0) * (NN / 4)) + ic * (PIX / 4);

    float4 ag = {0,0,0,0}, at_ = {0,0,0,0}, ap = {0,0,0,0};

    #pragma unroll 4
    for (int c = 0; c < NCC; ++c) {
        float4 v = xp[(size_t)c * (NN / 4) + tid];
        float wgc = gw[c0 + c], wtc = tw[c0 + c], wpc = pw[c0 + c];
        ag.x = fmaf(wgc, v.x, ag.x); ag.y = fmaf(wgc, v.y, ag.y);
        ag.z = fmaf(wgc, v.z, ag.z); ag.w = fmaf(wgc, v.w, ag.w);
        at_.x = fmaf(wtc, v.x, at_.x); at_.y = fmaf(wtc, v.y, at_.y);
        at_.z = fmaf(wtc, v.z, at_.z); at_.w = fmaf(wtc, v.w, at_.w);
        ap.x = fmaf(wpc, v.x, ap.x); ap.y = fmaf(wpc, v.y, ap.y);
        ap.z = fmaf(wpc, v.z, ap.z); ap.w = fmaf(wpc, v.w, ap.w);
        // per-channel avg partial: wave reduce
        float s = (v.x + v.y) + (v.z + v.w);
        for (int o = 32; o > 0; o >>= 1) s += __shfl_down(s, o);
        if (lane == 0)
            avgp[(size_t)(b * CC + c0 + c) * 8 + ic * 4 + wave] = s;
    }

    // write proj partials: pp[k][b][ic][cc][PIX]
    size_t base = (((size_t)b * 2 + ic) * NCHUNK + cc) * PIX + tid * 4;
    const size_t karr = (size_t)BB * 2 * NCHUNK * PIX;
    *reinterpret_cast<float4*>(pp + 0 * karr + base) = ag;
    *reinterpret_cast<float4*>(pp + 1 * karr + base) = at_;
    *reinterpret_cast<float4*>(pp + 2 * karr + base) = ap;
}

// ---------------- K2: reduce partials -> gx/tx/px ; avg -> SE -> Ac/Dc ----------------
// grid = 64 + 8. Blocks [0,64): (b, ic, quarter) proj finalize.
// Blocks [64,72): per-sample SE/affine.
__global__ __launch_bounds__(256) void k2(
    const float* __restrict__ pp, const float* __restrict__ avgp,
    const float* __restrict__ gb, const float* __restrict__ tb, const float* __restrict__ pb,
    const float* __restrict__ se1w, const float* __restrict__ se1b,
    const float* __restrict__ se2w, const float* __restrict__ se2b,
    const float* __restrict__ Ww, const float* __restrict__ Wb,
    const float* __restrict__ gamma, const float* __restrict__ beta,
    const float* __restrict__ mean, const float* __restrict__ var,
    float* __restrict__ gx, float* __restrict__ tx, float* __restrict__ px,
    float* __restrict__ Ac, float* __restrict__ Dc)
{
    int tid = threadIdx.x;
    if (blockIdx.x < 64) {
        int q  = blockIdx.x & 3;
        int ic = (blockIdx.x >> 2) & 1;
        int b  = blockIdx.x >> 3;
        int p  = q * 256 + tid;           // 0..1023 within chunk
        size_t base = (((size_t)b * 2 + ic) * NCHUNK) * PIX + p;
        const size_t karr = (size_t)BB * 2 * NCHUNK * PIX;
        float g = 0.f, t = 0.f, ph = 0.f;
        #pragma unroll 8
        for (int cc = 0; cc < NCHUNK; ++cc) {
            g  += pp[0 * karr + base + cc * PIX];
            t  += pp[1 * karr + base + cc * PIX];
            ph += pp[2 * karr + base + cc * PIX];
        }
        int o = b * NN + ic * PIX + p;
        gx[o] = g + gb[0];
        tx[o] = t + tb[0];
        px[o] = ph + pb[0];
        return;
    }

    // ---- SE / affine path ----
    int b = blockIdx.x - 64;
    __shared__ float sA[CC];
    __shared__ float sP[SEM][8];
    __shared__ float sM[SEM];
    for (int c = tid; c < CC; c += 256) {
        const float* ap = avgp + (size_t)(b * CC + c) * 8;
        float s = 0.f;
        #pragma unroll
        for (int k = 0; k < 8; ++k) s += ap[k];
        sA[c] = s * (1.0f / NN);
    }
    __syncthreads();
    {
        int m = tid >> 3, sub = tid & 7;
        const float* w1 = se1w + m * CC + sub * 64;
        const float* a1 = sA + sub * 64;
        float s = 0.f;
        #pragma unroll
        for (int k = 0; k < 64; ++k) s = fmaf(a1[k], w1[k], s);
        sP[m][sub] = s;
    }
    __syncthreads();
    if (tid < SEM) {
        float t = 0.f;
        #pragma unroll
        for (int k = 0; k < 8; ++k) t += sP[tid][k];
        sM[tid] = fmaxf(t + se1b[tid], 0.f);
    }
    __syncthreads();
    for (int c = tid; c < CC; c += 256) {
        float s2 = 0.f;
        #pragma unroll
        for (int m = 0; m < SEM; ++m) s2 = fmaf(sM[m], se2w[c * SEM + m], s2);
        s2 += se2b[c];
        float wcw = 1.f / (1.f + __expf(-s2));
        float inv = gamma[c] * rsqrtf(var[c] + BN_EPS);
        Ac[b * CC + c] = wcw * Ww[c] * inv;
        Dc[b * CC + c] = wcw * ((Wb[c] - mean[c]) * inv + beta[c]);
    }
}

// ---------------- K3: rank-1 softmax y (no-max, clamped) ----------------
// grid = 1024 blocks: 16 rows per block, 4 rows per wave.
__global__ __launch_bounds__(256) void k3(
    const float* __restrict__ gx, const float* __restrict__ tx,
    const float* __restrict__ px, float* __restrict__ y)
{
    __shared__ float2 pg[NN];
    int tid = threadIdx.x;
    int b  = blockIdx.x >> 7;                 // 128 blocks per sample
    int i0 = (blockIdx.x & 127) << 4;         // 16 rows per block
    for (int j = tid; j < NN; j += 256)
        pg[j] = make_float2(px[b * NN + j], gx[b * NN + j]);
    __syncthreads();

    int wave = tid >> 6, lane = tid & 63;
    int r0 = i0 + wave * 4;
    float t0 = tx[b * NN + r0 + 0];
    float t1 = tx[b * NN + r0 + 1];
    float t2 = tx[b * NN + r0 + 2];
    float t3 = tx[b * NN + r0 + 3];
    float s0 = 0.f, g0 = 0.f, s1 = 0.f, g1 = 0.f;
    float s2 = 0.f, g2 = 0.f, s3 = 0.f, g3 = 0.f;
    #pragma unroll 4
    for (int j = lane; j < NN; j += 64) {
        float2 v = pg[j];
        float e0 = __expf(fminf(t0 * v.x, 80.f));
        float e1 = __expf(fminf(t1 * v.x, 80.f));
        float e2 = __expf(fminf(t2 * v.x, 80.f));
        float e3 = __expf(fminf(t3 * v.x, 80.f));
        s0 += e0; g0 = fmaf(e0, v.y, g0);
        s1 += e1; g1 = fmaf(e1, v.y, g1);
        s2 += e2; g2 = fmaf(e2, v.y, g2);
        s3 += e3; g3 = fmaf(e3, v.y, g3);
    }
    for (int o = 32; o > 0; o >>= 1) {
        s0 += __shfl_down(s0, o); g0 += __shfl_down(g0, o);
        s1 += __shfl_down(s1, o); g1 += __shfl_down(g1, o);
        s2 += __shfl_down(s2, o); g2 += __shfl_down(g2, o);
        s3 += __shfl_down(s3, o); g3 += __shfl_down(g3, o);
    }
    if (lane == 0) {
        y[b * NN + r0 + 0] = g0 / s0;
        y[b * NN + r0 + 1] = g1 / s1;
        y[b * NN + r0 + 2] = g2 / s2;
        y[b * NN + r0 + 3] = g3 / s3;
    }
}

// ---------------- K4: epilogue out = A*y + D + x ----------------
__global__ __launch_bounds__(256) void k4(
    const float* __restrict__ x, const float* __restrict__ y,
    const float* __restrict__ Ac, const float* __restrict__ Dc,
    float* __restrict__ out)
{
    int bc = blockIdx.x;
    int b = bc >> 9;
    float a = Ac[bc], d = Dc[bc];
    const float4* x4 = reinterpret_cast<const float4*>(x) + (size_t)bc * (NN / 4);
    const float4* y4 = reinterpret_cast<const float4*>(y) + (size_t)b * (NN / 4);
    float4* o4 = reinterpret_cast<float4*>(out) + (size_t)bc * (NN / 4);
    int tid = threadIdx.x;
    #pragma unroll
    for (int k = 0; k < 2; ++k) {
        int idx = k * 256 + tid;
        float4 xv = x4[idx], yv = y4[idx], ov;
        ov.x = fmaf(a, yv.x, d) + xv.x;
        ov.y = fmaf(a, yv.y, d) + xv.y;
        ov.z = fmaf(a, yv.z, d) + xv.z;
        ov.w = fmaf(a, yv.w, d) + xv.w;
        o4[idx] = ov;
    }
}

extern "C" void kernel_launch(void* const* d_in, const int* in_sizes, int n_in,
                              void* d_out, int out_size, void* d_ws, size_t ws_size,
                              hipStream_t stream) {
    const float* x    = (const float*)d_in[0];
    const float* gw   = (const float*)d_in[1];
    const float* gb   = (const float*)d_in[2];
    const float* tw   = (const float*)d_in[3];
    const float* tb   = (const float*)d_in[4];
    const float* pw   = (const float*)d_in[5];
    const float* pb   = (const float*)d_in[6];
    const float* Ww   = (const float*)d_in[7];
    const float* Wb   = (const float*)d_in[8];
    const float* gam  = (const float*)d_in[9];
    const float* bet  = (const float*)d_in[10];
    const float* mu   = (const float*)d_in[11];
    const float* var  = (const float*)d_in[12];
    const float* se1w = (const float*)d_in[13];
    const float* se1b = (const float*)d_in[14];
    const float* se2w = (const float*)d_in[15];
    const float* se2b = (const float*)d_in[16];

    float* ws   = (float*)d_ws;
    float* pp   = ws; ws += 3 * BB * 2 * NCHUNK * PIX;  // 1.57M floats
    float* avgp = ws; ws += BB * CC * 8;
    float* gx   = ws; ws += BB * NN;
    float* tx   = ws; ws += BB * NN;
    float* px   = ws; ws += BB * NN;
    float* y    = ws; ws += BB * NN;
    float* Ac   = ws; ws += BB * CC;
    float* Dc   = ws; ws += BB * CC;
    float* out  = (float*)d_out;

    k1<<<BB * NCHUNK * 2, 256, 0, stream>>>(x, gw, tw, pw, pp, avgp);
    k2<<<64 + BB, 256, 0, stream>>>(pp, avgp, gb, tb, pb, se1w, se1b, se2w, se2b,
                                    Ww, Wb, gam, bet, mu, var, gx, tx, px, Ac, Dc);
    k3<<<BB * 128, 256, 0, stream>>>(gx, tx, px, y);
    k4<<<BB * CC, 256, 0, stream>>>(x, y, Ac, Dc, out);
}

// Round 4
// 39.189 us; speedup vs baseline: 1.8975x; 1.0848x over previous
//
#include <hip/hip_runtime.h>

#define BB 8
#define CC 512
#define NN 2048
#define SEM 32
#define BN_EPS 1e-5f

#define NCC 16              // channels per chunk
#define NCHUNK (CC / NCC)   // 32 chunks
#define PIX 1024            // pixels per chunk (256 threads * float4)

// ---------------- K1: full-BW pass: proj partials + avg partials ----------------
// grid = BB * NCHUNK * 2 = 512 blocks. Block handles (b, cc: 16 channels, ic: 1024 pixels).
// Avg reduction: per-thread scalar per channel, ONE ILP-interleaved wave reduce at end.
__global__ __launch_bounds__(256) void k1(const float* __restrict__ x,
    const float* __restrict__ gw, const float* __restrict__ tw, const float* __restrict__ pw,
    float* __restrict__ pp,      // [3][BB][2][NCHUNK][PIX]
    float* __restrict__ avgp)    // [BB*CC][8]
{
    int tid = threadIdx.x;
    int wave = tid >> 6, lane = tid & 63;
    int blk = blockIdx.x;
    int ic = blk & 1;
    int cc = (blk >> 1) & (NCHUNK - 1);
    int b  = blk >> 6;
    int c0 = cc * NCC;

    const float4* xp = reinterpret_cast<const float4*>(x)
                     + ((size_t)(b * CC + c0) * (NN / 4)) + ic * (PIX / 4);

    float4 ag = {0,0,0,0}, at_ = {0,0,0,0}, ap = {0,0,0,0};
    float s[NCC];

    #pragma unroll
    for (int c = 0; c < NCC; ++c) {
        float4 v = xp[(size_t)c * (NN / 4) + tid];
        float wgc = gw[c0 + c], wtc = tw[c0 + c], wpc = pw[c0 + c];
        ag.x = fmaf(wgc, v.x, ag.x); ag.y = fmaf(wgc, v.y, ag.y);
        ag.z = fmaf(wgc, v.z, ag.z); ag.w = fmaf(wgc, v.w, ag.w);
        at_.x = fmaf(wtc, v.x, at_.x); at_.y = fmaf(wtc, v.y, at_.y);
        at_.z = fmaf(wtc, v.z, at_.z); at_.w = fmaf(wtc, v.w, at_.w);
        ap.x = fmaf(wpc, v.x, ap.x); ap.y = fmaf(wpc, v.y, ap.y);
        ap.z = fmaf(wpc, v.z, ap.z); ap.w = fmaf(wpc, v.w, ap.w);
        s[c] = (v.x + v.y) + (v.z + v.w);   // per-channel per-thread partial
    }

    // write proj partials: pp[k][b][ic][cc][PIX]
    size_t base = (((size_t)b * 2 + ic) * NCHUNK + cc) * PIX + tid * 4;
    const size_t karr = (size_t)BB * 2 * NCHUNK * PIX;
    *reinterpret_cast<float4*>(pp + 0 * karr + base) = ag;
    *reinterpret_cast<float4*>(pp + 1 * karr + base) = at_;
    *reinterpret_cast<float4*>(pp + 2 * karr + base) = ap;

    // wave-reduce 16 channels with ILP across channels (6 rounds x 16 independent)
    #pragma unroll
    for (int o = 32; o > 0; o >>= 1) {
        #pragma unroll
        for (int c = 0; c < NCC; ++c)
            s[c] += __shfl_down(s[c], o);
    }
    if (lane == 0) {
        #pragma unroll
        for (int c = 0; c < NCC; ++c)
            avgp[(size_t)(b * CC + c0 + c) * 8 + ic * 4 + wave] = s[c];
    }
}

// ---------------- K2: reduce proj partials -> gx/tx/px ----------------
// grid = 128 blocks: (b, ic, half). Thread handles 2 pixels via float2 loads.
__global__ __launch_bounds__(256) void k2(
    const float* __restrict__ pp,
    const float* __restrict__ gb, const float* __restrict__ tb, const float* __restrict__ pb,
    float* __restrict__ gx, float* __restrict__ tx, float* __restrict__ px)
{
    int tid = threadIdx.x;
    int half = blockIdx.x & 1;
    int ic   = (blockIdx.x >> 1) & 1;
    int b    = blockIdx.x >> 2;
    int p    = half * 512 + tid * 2;      // pixel within 1024-px chunk
    size_t base = ((((size_t)b * 2 + ic) * NCHUNK) * PIX + p) / 2;  // float2 index
    const size_t karr2 = (size_t)BB * 2 * NCHUNK * PIX / 2;
    const float2* pp2 = reinterpret_cast<const float2*>(pp);
    float2 g = {0,0}, t = {0,0}, ph = {0,0};
    #pragma unroll 8
    for (int cc = 0; cc < NCHUNK; ++cc) {
        float2 a = pp2[0 * karr2 + base + cc * (PIX / 2)];
        float2 c = pp2[1 * karr2 + base + cc * (PIX / 2)];
        float2 d = pp2[2 * karr2 + base + cc * (PIX / 2)];
        g.x += a.x;  g.y += a.y;
        t.x += c.x;  t.y += c.y;
        ph.x += d.x; ph.y += d.y;
    }
    int o = b * NN + ic * PIX + p;
    float gbv = gb[0], tbv = tb[0], pbv = pb[0];
    *reinterpret_cast<float2*>(gx + o) = make_float2(g.x + gbv, g.y + gbv);
    *reinterpret_cast<float2*>(tx + o) = make_float2(t.x + tbv, t.y + tbv);
    *reinterpret_cast<float2*>(px + o) = make_float2(ph.x + pbv, ph.y + pbv);
}

// ---------------- K3: rank-1 softmax y (no-max, clamped) + SE/affine ----------------
// grid = 1024 + 8. Blocks [0,1024): 16 rows each. Blocks [1024,1032): SE -> Ac/Dc.
__global__ __launch_bounds__(256) void k3(
    const float* __restrict__ gx, const float* __restrict__ tx,
    const float* __restrict__ px, const float* __restrict__ avgp,
    const float* __restrict__ se1w, const float* __restrict__ se1b,
    const float* __restrict__ se2w, const float* __restrict__ se2b,
    const float* __restrict__ Ww, const float* __restrict__ Wb,
    const float* __restrict__ gamma, const float* __restrict__ beta,
    const float* __restrict__ mean, const float* __restrict__ var,
    float* __restrict__ y, float* __restrict__ Ac, float* __restrict__ Dc)
{
    int tid = threadIdx.x;

    if (blockIdx.x >= 1024) {
        // ---- SE / affine path ----
        int b = blockIdx.x - 1024;
        __shared__ float sA[CC];
        __shared__ float sP[SEM][8];
        __shared__ float sM[SEM];
        for (int c = tid; c < CC; c += 256) {
            const float* apt = avgp + (size_t)(b * CC + c) * 8;
            float s = 0.f;
            #pragma unroll
            for (int k = 0; k < 8; ++k) s += apt[k];
            sA[c] = s * (1.0f / NN);
        }
        __syncthreads();
        {
            int m = tid >> 3, sub = tid & 7;
            const float* w1 = se1w + m * CC + sub * 64;
            const float* a1 = sA + sub * 64;
            float s = 0.f;
            #pragma unroll
            for (int k = 0; k < 64; ++k) s = fmaf(a1[k], w1[k], s);
            sP[m][sub] = s;
        }
        __syncthreads();
        if (tid < SEM) {
            float t = 0.f;
            #pragma unroll
            for (int k = 0; k < 8; ++k) t += sP[tid][k];
            sM[tid] = fmaxf(t + se1b[tid], 0.f);
        }
        __syncthreads();
        for (int c = tid; c < CC; c += 256) {
            float s2 = 0.f;
            #pragma unroll
            for (int m = 0; m < SEM; ++m) s2 = fmaf(sM[m], se2w[c * SEM + m], s2);
            s2 += se2b[c];
            float wcw = 1.f / (1.f + __expf(-s2));
            float inv = gamma[c] * rsqrtf(var[c] + BN_EPS);
            Ac[b * CC + c] = wcw * Ww[c] * inv;
            Dc[b * CC + c] = wcw * ((Wb[c] - mean[c]) * inv + beta[c]);
        }
        return;
    }

    // ---- softmax-y path: 16 rows per block, 4 per wave ----
    __shared__ float2 pg[NN];
    int b  = blockIdx.x >> 7;                 // 128 blocks per sample
    int i0 = (blockIdx.x & 127) << 4;
    for (int j = tid; j < NN; j += 256)
        pg[j] = make_float2(px[b * NN + j], gx[b * NN + j]);
    __syncthreads();

    int wave = tid >> 6, lane = tid & 63;
    int r0 = i0 + wave * 4;
    float t0 = tx[b * NN + r0 + 0];
    float t1 = tx[b * NN + r0 + 1];
    float t2 = tx[b * NN + r0 + 2];
    float t3 = tx[b * NN + r0 + 3];
    float s0 = 0.f, g0 = 0.f, s1 = 0.f, g1 = 0.f;
    float s2 = 0.f, g2 = 0.f, s3 = 0.f, g3 = 0.f;
    #pragma unroll 4
    for (int j = lane; j < NN; j += 64) {
        float2 v = pg[j];
        float e0 = __expf(fminf(t0 * v.x, 80.f));
        float e1 = __expf(fminf(t1 * v.x, 80.f));
        float e2 = __expf(fminf(t2 * v.x, 80.f));
        float e3 = __expf(fminf(t3 * v.x, 80.f));
        s0 += e0; g0 = fmaf(e0, v.y, g0);
        s1 += e1; g1 = fmaf(e1, v.y, g1);
        s2 += e2; g2 = fmaf(e2, v.y, g2);
        s3 += e3; g3 = fmaf(e3, v.y, g3);
    }
    for (int o = 32; o > 0; o >>= 1) {
        s0 += __shfl_down(s0, o); g0 += __shfl_down(g0, o);
        s1 += __shfl_down(s1, o); g1 += __shfl_down(g1, o);
        s2 += __shfl_down(s2, o); g2 += __shfl_down(g2, o);
        s3 += __shfl_down(s3, o); g3 += __shfl_down(g3, o);
    }
    if (lane == 0) {
        y[b * NN + r0 + 0] = g0 / s0;
        y[b * NN + r0 + 1] = g1 / s1;
        y[b * NN + r0 + 2] = g2 / s2;
        y[b * NN + r0 + 3] = g3 / s3;
    }
}

// ---------------- K4: epilogue out = A*y + D + x ----------------
__global__ __launch_bounds__(256) void k4(
    const float* __restrict__ x, const float* __restrict__ y,
    const float* __restrict__ Ac, const float* __restrict__ Dc,
    float* __restrict__ out)
{
    int bc = blockIdx.x;
    int b = bc >> 9;
    float a = Ac[bc], d = Dc[bc];
    const float4* x4 = reinterpret_cast<const float4*>(x) + (size_t)bc * (NN / 4);
    const float4* y4 = reinterpret_cast<const float4*>(y) + (size_t)b * (NN / 4);
    float4* o4 = reinterpret_cast<float4*>(out) + (size_t)bc * (NN / 4);
    int tid = threadIdx.x;
    #pragma unroll
    for (int k = 0; k < 2; ++k) {
        int idx = k * 256 + tid;
        float4 xv = x4[idx], yv = y4[idx], ov;
        ov.x = fmaf(a, yv.x, d) + xv.x;
        ov.y = fmaf(a, yv.y, d) + xv.y;
        ov.z = fmaf(a, yv.z, d) + xv.z;
        ov.w = fmaf(a, yv.w, d) + xv.w;
        o4[idx] = ov;
    }
}

extern "C" void kernel_launch(void* const* d_in, const int* in_sizes, int n_in,
                              void* d_out, int out_size, void* d_ws, size_t ws_size,
                              hipStream_t stream) {
    const float* x    = (const float*)d_in[0];
    const float* gw   = (const float*)d_in[1];
    const float* gb   = (const float*)d_in[2];
    const float* tw   = (const float*)d_in[3];
    const float* tb   = (const float*)d_in[4];
    const float* pw   = (const float*)d_in[5];
    const float* pb   = (const float*)d_in[6];
    const float* Ww   = (const float*)d_in[7];
    const float* Wb   = (const float*)d_in[8];
    const float* gam  = (const float*)d_in[9];
    const float* bet  = (const float*)d_in[10];
    const float* mu   = (const float*)d_in[11];
    const float* var  = (const float*)d_in[12];
    const float* se1w = (const float*)d_in[13];
    const float* se1b = (const float*)d_in[14];
    const float* se2w = (const float*)d_in[15];
    const float* se2b = (const float*)d_in[16];

    float* ws   = (float*)d_ws;
    float* pp   = ws; ws += 3 * BB * 2 * NCHUNK * PIX;
    float* avgp = ws; ws += BB * CC * 8;
    float* gx   = ws; ws += BB * NN;
    float* tx   = ws; ws += BB * NN;
    float* px   = ws; ws += BB * NN;
    float* y    = ws; ws += BB * NN;
    float* Ac   = ws; ws += BB * CC;
    float* Dc   = ws; ws += BB * CC;
    float* out  = (float*)d_out;

    k1<<<BB * NCHUNK * 2, 256, 0, stream>>>(x, gw, tw, pw, pp, avgp);
    k2<<<BB * 2 * 2, 256, 0, stream>>>(pp, gb, tb, pb, gx, tx, px);
    k3<<<1024 + BB, 256, 0, stream>>>(gx, tx, px, avgp, se1w, se1b, se2w, se2b,
                                      Ww, Wb, gam, bet, mu, var, y, Ac, Dc);
    k4<<<BB * CC, 256, 0, stream>>>(x, y, Ac, Dc, out);
}